// Round 11
// baseline (600.126 us; speedup 1.0000x reference)
//
#include <hip/hip_runtime.h>
#include <hip/hip_bf16.h>

using u16 = unsigned short;
using u32 = unsigned int;

#define BB 512
#define SS 100
#define LL 30
#define DD 400
#define MM 128
#define HH 20
#define DHH 20

typedef short v8s __attribute__((ext_vector_type(8)));   // 8 bf16 = 4 VGPR
typedef float v4f __attribute__((ext_vector_type(4)));   // MFMA 16x16 acc

__device__ __forceinline__ float lo2f(u32 u) { return __uint_as_float(u << 16); }
__device__ __forceinline__ float hi2f(u32 u) { return __uint_as_float(u & 0xffff0000u); }
__device__ __forceinline__ float bf2f(u16 h) { return __uint_as_float(((u32)h) << 16); }
__device__ __forceinline__ u16 f2bf(float f) {
  u32 u = __float_as_uint(f);
  u += 0x7fffu + ((u >> 16) & 1u);
  return (u16)(u >> 16);
}
__device__ __forceinline__ u32 packf2(float a, float b) {
  return (u32)f2bf(a) | (((u32)f2bf(b)) << 16);
}

// ---------------------------------------------------------------------------
// K0a: slice-reorganize the f32 emb table into 8 XCD-affine bf16 slice
// tables: embS[slice][row][25 u32] (5 MB per slice).  XCD-AFFINE: block
// bid%8 == slice -> the slice's WRITES land in the owning XCD's L2.
// Also zeros alpha.
// ---------------------------------------------------------------------------
__global__ __launch_bounds__(256) void k_slice(const float* __restrict__ emb,
                                               u32* __restrict__ embS,
                                               float* __restrict__ alpha) {
  const int bid = blockIdx.x;                // 39064 blocks
  const int slice = bid & 7;
  const int inner = (bid >> 3) * 256 + threadIdx.x;   // 0..1249999 within slice
  if (bid < 200) alpha[bid * 256 + threadIdx.x] = 0.f;
  if (inner < 1250000) {
    const int c = inner % 25;
    const int row = inner / 25;
    const float2 v = *(const float2*)&emb[(size_t)row * DD + (slice * 25 + c) * 2];
    embS[(size_t)slice * 1250000u + inner] = packf2(v.x, v.y);
  }
}

// ---------------------------------------------------------------------------
// K0b: transpose-convert, all four weight matrices in one launch.
// ---------------------------------------------------------------------------
__global__ __launch_bounds__(256) void k_trans_all(const float* __restrict__ wq,
    const float* __restrict__ wk, const float* __restrict__ wv,
    const float* __restrict__ f1w, u16* __restrict__ wt, u16* __restrict__ wtf) {
  __shared__ float ts[32][33];
  const int z = blockIdx.z;
  const float* src = (z == 0) ? wq : (z == 1) ? wk : (z == 2) ? wv : f1w;
  u16* dst = (z < 3) ? (wt + (size_t)z * 160000) : wtf;
  const int N = (z < 3) ? 400 : 128;
  const int K = 400;
  const int t = threadIdx.x;
  const int n0 = blockIdx.x * 32, k0 = blockIdx.y * 32;
  const int c = t & 31, r8 = t >> 5;
#pragma unroll
  for (int i = 0; i < 4; ++i) {
    const int k = k0 + r8 + i * 8, n = n0 + c;
    ts[r8 + i * 8][c] = (k < K && n < N) ? src[(size_t)k * N + n] : 0.f;
  }
  __syncthreads();
#pragma unroll
  for (int i = 0; i < 4; ++i) {
    const int n = n0 + r8 + i * 8, k = k0 + c;
    if (n < N && k < K) dst[(size_t)n * K + k] = f2bf(ts[c][r8 + i * 8]);
  }
}

// ---------------------------------------------------------------------------
// K1: embedding gather + mean pool over XCD-affine slice tables.
// (round-6 form — accepted floor: single pass, unconditional gathers,
//  unroll 6 -> 12 loads in flight, VGPR ~24.)
// ---------------------------------------------------------------------------
__global__ __launch_bounds__(256) void k_embed_s(const int* __restrict__ uc,
                                                 const u32* __restrict__ embS,
                                                 u32* __restrict__ click) {
  __shared__ int sIdx[600];                  // 20 rows x 30 indices
  const int slice = blockIdx.x & 7;
  const int chunk = blockIdx.x >> 3;         // 0..2559
  const int bs0 = chunk * 20;
  const int t = threadIdx.x;
  for (int i = t; i < 600; i += 256) sIdx[i] = uc[(size_t)bs0 * LL + i];
  __syncthreads();
  if (t >= 250) return;
  const int g = t / 25, c = t % 25;
  const u32* base = embS + (size_t)slice * 50000u * 25u + c;
  float a0 = 0.f, a1 = 0.f, b0 = 0.f, b1 = 0.f;
  const int* i0 = &sIdx[g * 30];
  const int* i1 = &sIdx[(g + 10) * 30];
#pragma unroll 6
  for (int l = 0; l < LL; ++l) {
    const u32 v0 = base[(size_t)i0[l] * 25];
    const u32 v1 = base[(size_t)i1[l] * 25];
    a0 += lo2f(v0); a1 += hi2f(v0);
    b0 += lo2f(v1); b1 += hi2f(v1);
  }
  const float s = 1.0f / (float)LL;
  click[(size_t)(bs0 + g) * 200 + slice * 25 + c]      = packf2(a0 * s, a1 * s);
  click[(size_t)(bs0 + g + 10) * 200 + slice * 25 + c] = packf2(b0 * s, b1 * s);
}

// ---------------------------------------------------------------------------
// K2: QKV projection, bf16 MFMA.  1D grid 3000.
//  - XCD-affine mapping: xcd = bid%8 owns m-tiles [xcd*25, xcd*25+25).
//  - BK=64: the swizzled LDS rows are already 64 u16 (128 B) — using the
//    full row halves the kt count (13->7) and barrier count (26->14) at
//    IDENTICAL LDS size/occupancy.  Two half-K fragment batches are read
//    and issued sequentially inside each phase (register pressure flat).
//  - XOR-16B-unit swizzle on write and read -> conflict-free ds_read_b128.
// ROW-MAJOR output C[51200][1200].
// ---------------------------------------------------------------------------
__global__ __launch_bounds__(256) void k_qkv_mfma(const u16* __restrict__ A,
    const u16* __restrict__ Wt, u16* __restrict__ C) {
  __shared__ u16 As[256 * 64];   // row r at As[r*64], 16B-unit swizzled
  __shared__ u16 Bs[80 * 64];
  const int t = threadIdx.x;
  const int wave = t >> 6, lane = t & 63;
  const int q = lane >> 4, l16 = lane & 15;
  const int bid = blockIdx.x;                // 0..2999
  const int xcd = bid & 7, j = bid >> 3;     // j 0..374
  const int m_local = j / 15, mtn = j % 15;
  const int m0 = (xcd * 25 + m_local) * 256;
  const int mat = mtn / 5, ntile = mtn % 5;
  const int nb = ntile * 80;
  const u16* Bt = Wt + (size_t)(mat * 400 + nb) * 400;
  const int mw = wave * 64;

  v4f acc[4][5];
#pragma unroll
  for (int i = 0; i < 4; ++i)
#pragma unroll
    for (int j2 = 0; j2 < 5; ++j2) acc[i][j2] = (v4f){0.f, 0.f, 0.f, 0.f};

  for (int kt = 0; kt < 7; ++kt) {
    const int k0 = kt * 64;
    // stage A: 256 rows x 8 units (2048 uint4)
#pragma unroll
    for (int i = 0; i < 8; ++i) {
      const int id = i * 256 + t;
      const int r = id >> 3, u = id & 7;     // u = 16B unit (8 u16)
      uint4 val = make_uint4(0u, 0u, 0u, 0u);
      if (k0 + u * 8 < 400) val = *(const uint4*)&A[(size_t)(m0 + r) * 400 + k0 + u * 8];
      *(uint4*)&As[r * 64 + ((u ^ (r & 7)) << 3)] = val;
    }
    // stage B: 80 rows x 8 units (640 uint4)
#pragma unroll
    for (int i = 0; i < 3; ++i) {
      const int id = i * 256 + t;
      if (id < 640) {
        const int n = id >> 3, u = id & 7;
        uint4 val = make_uint4(0u, 0u, 0u, 0u);
        if (k0 + u * 8 < 400) val = *(const uint4*)&Bt[(size_t)n * 400 + k0 + u * 8];
        *(uint4*)&Bs[n * 64 + ((u ^ (n & 7)) << 3)] = val;
      }
    }
    __syncthreads();
#pragma unroll
    for (int half = 0; half < 2; ++half) {
      const int qh = q + half * 4;           // unit 0-3 (k 0-31) or 4-7 (k 32-63)
      v8s a[4], b[5];
#pragma unroll
      for (int ms = 0; ms < 4; ++ms) {
        const int ra = mw + ms * 16 + l16;
        a[ms] = *(const v8s*)&As[ra * 64 + ((qh ^ (ra & 7)) << 3)];
      }
#pragma unroll
      for (int ns = 0; ns < 5; ++ns) {
        const int rb = ns * 16 + l16;
        b[ns] = *(const v8s*)&Bs[rb * 64 + ((qh ^ (rb & 7)) << 3)];
      }
#pragma unroll
      for (int ms = 0; ms < 4; ++ms)
#pragma unroll
        for (int ns = 0; ns < 5; ++ns)
          acc[ms][ns] = __builtin_amdgcn_mfma_f32_16x16x32_bf16(a[ms], b[ns], acc[ms][ns], 0, 0, 0);
    }
    __syncthreads();
  }
  // epilogue: row-major coalesced store.  D layout col = l16, row = q*4+reg
#pragma unroll
  for (int ms = 0; ms < 4; ++ms)
#pragma unroll
    for (int ns = 0; ns < 5; ++ns) {
      const v4f c = acc[ms][ns];
      const int gcol = mat * 400 + nb + ns * 16 + l16;
#pragma unroll
      for (int reg = 0; reg < 4; ++reg) {
        const int m = m0 + mw + ms * 16 + q * 4 + reg;
        C[(size_t)m * 1200 + gcol] = f2bf(c[reg]);
      }
    }
}

// ---------------------------------------------------------------------------
// K2b: V transpose from row-major C.  Chunk c = h*512+b; input rows
// C[b*100+s][800+h*20 .. +20), output [20][100] contiguous at c*2000 u16.
// LDS tile padded [100][22] (gcd(11,32)=1) -> conflict-free.
// ---------------------------------------------------------------------------
__global__ __launch_bounds__(256) void k_vt(const u32* __restrict__ c32,
                                            u32* __restrict__ vout) {
  __shared__ u16 Vs[4][100][22];
  const int wave = threadIdx.x >> 6, lane = threadIdx.x & 63;
  const int c = blockIdx.x * 4 + wave;       // h*512+b
  const int h = c >> 9, b = c & 511;
  const u32* in = c32 + (size_t)b * 60000 + 400 + h * 10;
  u32* out = vout + (size_t)c * 1000;
  for (int i = lane; i < 1000; i += 64) {
    const int s = i / 10, dp = i % 10;
    *(u32*)&Vs[wave][s][dp * 2] = in[s * 600 + dp];
  }
  __syncthreads();
  for (int o = lane; o < 1000; o += 64) {
    const int d = o / 50, sc = o % 50;
    out[o] = (u32)Vs[wave][2 * sc][d] | (((u32)Vs[wave][2 * sc + 1][d]) << 16);
  }
}

// ---------------------------------------------------------------------------
// K3: MFMA attention, swapped-QK / register-softmax form.
// Q/K read from row-major C (cols h*20.. / 400+h*20..); V^T from k_vt.
// One block per (b,h), 4 waves, LDS = K only (8.96 KB), single barrier.
// ---------------------------------------------------------------------------
__global__ __launch_bounds__(256) void k_attn_mfma(const u32* __restrict__ c32,
    const u16* __restrict__ vtg, const int* __restrict__ seq,
    u16* __restrict__ ctxg) {
  __shared__ u32 Ks[2240];                 // [112 rows][20 u32] zero-padded K
  const int b = blockIdx.x / HH, h = blockIdx.x % HH;
  const int t = threadIdx.x;
  const int wave = t >> 6, lane = t & 63;
  const int quad = lane >> 4, l16 = lane & 15;
  const int len = seq[b];
  const u32* qp = c32 + (size_t)b * 60000 + h * 10;        // Q cols
  const u32* kp = qp + 200;                                // K cols (+400 u16)
  const u32* vb = (const u32*)(vtg + (size_t)(h * 512 + b) * 2000);

  // V^T B-fragments direct from global, hoisted across both mt iterations.
  uint2 vfr[2][7];
#pragma unroll
  for (int dt = 0; dt < 2; ++dt) {
    const int d = dt * 16 + l16;
#pragma unroll
    for (int nt = 0; nt < 7; ++nt)
      vfr[dt][nt] = *(const uint2*)(vb + d * 50 + nt * 8 + quad * 2);
  }
  // stage K into LDS, zero-padded
  for (int id = t; id < 2240; id += 256) {
    const int r = id / 20, c = id % 20;
    Ks[id] = (r < 100 && c < 10) ? kp[(size_t)r * 600 + c] : 0u;
  }
  __syncthreads();

  const float sc = 0.2236067977499790f;  // 1/sqrt(20)
  u16* cb = ctxg + (size_t)b * SS * DD + h * DHH;
  for (int mi = 0; mi < 2; ++mi) {
    const int mt = wave + mi * 4;
    if (mt >= 7) break;
    // Q fragment (B-slot): row mt*16+l16 (clamped; rows>=100 discarded),
    // k = quad*8..+8 (k>=20 garbage annihilated by K's zero pad).
    const int qrow = mt * 16 + l16;
    const int qr = (qrow < 100) ? qrow : 0;
    union { uint2 u[2]; v8s v; } qf;
    qf.u[0] = *(const uint2*)(qp + (size_t)qr * 600 + quad * 4);
    qf.u[1] = *(const uint2*)(qp + (size_t)qr * 600 + quad * 4 + 2);
    // swapped QK^T: acc[nt][reg] = S[q = mt*16+l16][k = nt*16+quad*4+reg]
    v4f acc[7];
#pragma unroll
    for (int nt = 0; nt < 7; ++nt) {
      const v8s kf = *(const v8s*)&Ks[(nt * 16 + l16) * 20 + quad * 4];
      acc[nt] = __builtin_amdgcn_mfma_f32_16x16x32_bf16(kf, qf.v, (v4f){0.f,0.f,0.f,0.f}, 0, 0, 0);
    }
    // in-register row softmax (row spread across the 4 quads only)
    float mx = -3.0e38f;
#pragma unroll
    for (int nt = 0; nt < 7; ++nt)
#pragma unroll
      for (int reg = 0; reg < 4; ++reg) {
        const int k = nt * 16 + quad * 4 + reg;
        const float v = acc[nt][reg] * sc + ((k < len) ? 1.0f : -1e9f);
        acc[nt][reg] = v;
        mx = fmaxf(mx, v);
      }
    mx = fmaxf(mx, __shfl_xor(mx, 16));
    mx = fmaxf(mx, __shfl_xor(mx, 32));
    float sum = 0.f;
#pragma unroll
    for (int nt = 0; nt < 7; ++nt)
#pragma unroll
      for (int reg = 0; reg < 4; ++reg) {
        const float e = __expf(acc[nt][reg] - mx);
        acc[nt][reg] = e;
        sum += e;
      }
    sum += __shfl_xor(sum, 16);
    sum += __shfl_xor(sum, 32);
    const float inv = 1.0f / sum;
    // PV: P already in A-fragment layout (k = quad*4+j); zero-extended
    // 16x16x32 MFMAs (operands in slots quad*8+{0..3}, zeros above).
    v4f o0 = (v4f){0.f, 0.f, 0.f, 0.f}, o1 = o0;
#pragma unroll
    for (int nt = 0; nt < 7; ++nt) {
      union { u32 u[4]; v8s v; } pa, vb0, vb1;
      pa.u[0] = packf2(acc[nt][0] * inv, acc[nt][1] * inv);
      pa.u[1] = packf2(acc[nt][2] * inv, acc[nt][3] * inv);
      pa.u[2] = 0u; pa.u[3] = 0u;
      vb0.u[0] = vfr[0][nt].x; vb0.u[1] = vfr[0][nt].y; vb0.u[2] = 0u; vb0.u[3] = 0u;
      vb1.u[0] = vfr[1][nt].x; vb1.u[1] = vfr[1][nt].y; vb1.u[2] = 0u; vb1.u[3] = 0u;
      o0 = __builtin_amdgcn_mfma_f32_16x16x32_bf16(pa.v, vb0.v, o0, 0, 0, 0);
      o1 = __builtin_amdgcn_mfma_f32_16x16x32_bf16(pa.v, vb1.v, o1, 0, 0, 0);
    }
#pragma unroll
    for (int reg = 0; reg < 4; ++reg) {
      const int q2 = mt * 16 + quad * 4 + reg;
      if (q2 < 100) {
        cb[(size_t)q2 * DD + l16] = f2bf(o0[reg]);
        if (l16 < 4) cb[(size_t)q2 * DD + 16 + l16] = f2bf(o1[reg]);
      }
    }
  }
}

// ---------------------------------------------------------------------------
// K4: alpha = tanh(ctx @ fc1_w + f1b) · f2w, fused.
// ---------------------------------------------------------------------------
__global__ __launch_bounds__(256) void k_fc1_alpha(const u16* __restrict__ A,
    const u16* __restrict__ Bt, const float* __restrict__ f1b,
    const float* __restrict__ f2w, float* __restrict__ alpha) {
  __shared__ u16 As[128][40];
  __shared__ u16 Bs[64][40];
  const int t = threadIdx.x;
  const int wave = t >> 6, lane = t & 63;
  const int quad = lane >> 4, l16 = lane & 15;
  const int m0 = blockIdx.x * 128;
  const int nb = blockIdx.y * 64;
  const int mw = wave * 32;
  v4f acc[2][4];
#pragma unroll
  for (int i = 0; i < 2; ++i)
#pragma unroll
    for (int j = 0; j < 4; ++j) acc[i][j] = (v4f){0.f, 0.f, 0.f, 0.f};

  for (int kt = 0; kt < 13; ++kt) {
    const int k0 = kt * 32;
#pragma unroll
    for (int i = 0; i < 2; ++i) {
      const int id = i * 256 + t;
      const int r = id >> 2, ko = (id & 3) * 8;
      uint4 val = make_uint4(0u, 0u, 0u, 0u);
      if (k0 + ko < 400) val = *(const uint4*)&A[(size_t)(m0 + r) * 400 + k0 + ko];
      *(uint4*)&As[r][ko] = val;
    }
    {
      const int r = t >> 2, ko = (t & 3) * 8;
      uint4 val = make_uint4(0u, 0u, 0u, 0u);
      if (k0 + ko < 400) val = *(const uint4*)&Bt[(size_t)(nb + r) * 400 + k0 + ko];
      *(uint4*)&Bs[r][ko] = val;
    }
    __syncthreads();
    v8s a[2], b[4];
#pragma unroll
    for (int ms = 0; ms < 2; ++ms) a[ms] = *(const v8s*)&As[mw + ms * 16 + l16][quad * 8];
#pragma unroll
    for (int ns = 0; ns < 4; ++ns) b[ns] = *(const v8s*)&Bs[ns * 16 + l16][quad * 8];
#pragma unroll
    for (int ms = 0; ms < 2; ++ms)
#pragma unroll
      for (int ns = 0; ns < 4; ++ns)
        acc[ms][ns] = __builtin_amdgcn_mfma_f32_16x16x32_bf16(a[ms], b[ns], acc[ms][ns], 0, 0, 0);
    __syncthreads();
  }
  float fwv[4], fbv[4];
#pragma unroll
  for (int ns = 0; ns < 4; ++ns) {
    fwv[ns] = f2w[nb + ns * 16 + l16];
    fbv[ns] = f1b[nb + ns * 16 + l16];
  }
#pragma unroll
  for (int ms = 0; ms < 2; ++ms)
#pragma unroll
    for (int reg = 0; reg < 4; ++reg) {
      float p = 0.f;
#pragma unroll
      for (int ns = 0; ns < 4; ++ns)
        p += tanhf(acc[ms][ns][reg] + fbv[ns]) * fwv[ns];
#pragma unroll
      for (int o = 1; o < 16; o <<= 1) p += __shfl_xor(p, o);
      if (l16 == 0)
        atomicAdd(&alpha[m0 + mw + ms * 16 + quad * 4 + reg], p);
    }
}

// ---------------------------------------------------------------------------
// K5: additive attention pooling from alpha.  One block per batch row.
// ---------------------------------------------------------------------------
__global__ __launch_bounds__(256) void k_pool(const float* __restrict__ alpha,
    const float* __restrict__ f2b, const int* __restrict__ seq,
    const u16* __restrict__ ctxg, float* __restrict__ out) {
  const int b = blockIdx.x;
  const int t = threadIdx.x, w = t >> 6, lane = t & 63;
  __shared__ float wts[SS];
  const int len = seq[b];
  const float bias = f2b[0];
  if (t < SS) wts[t] = alpha[b * SS + t] + bias + ((t < len) ? 1.0f : -1e9f);
  __syncthreads();
  if (w == 0) {
    const float v0 = wts[lane];
    const float v1 = (lane + 64 < SS) ? wts[lane + 64] : -3.0e38f;
    float mx = fmaxf(v0, v1);
#pragma unroll
    for (int o = 32; o > 0; o >>= 1) mx = fmaxf(mx, __shfl_xor(mx, o));
    const float e0 = __expf(v0 - mx);
    const float e1 = (lane + 64 < SS) ? __expf(v1 - mx) : 0.f;
    float sm = e0 + e1;
#pragma unroll
    for (int o = 32; o > 0; o >>= 1) sm += __shfl_xor(sm, o);
    const float inv = 1.0f / sm;
    wts[lane] = e0 * inv;
    if (lane + 64 < SS) wts[lane + 64] = e1 * inv;
  }
  __syncthreads();
  for (int d = t; d < DD; d += 256) {
    float acc = 0.f;
    const u16* cb = ctxg + (size_t)b * SS * DD + d;
    for (int s = 0; s < SS; ++s) acc += wts[s] * bf2f(cb[(size_t)s * DD]);
    out[(size_t)b * DD + d] = acc;
  }
}

// ---------------------------------------------------------------------------
extern "C" void kernel_launch(void* const* d_in, const int* in_sizes, int n_in,
                              void* d_out, int out_size, void* d_ws, size_t ws_size,
                              hipStream_t stream) {
  const int*   uc  = (const int*)d_in[0];
  const int*   seq = (const int*)d_in[1];
  const float* emb = (const float*)d_in[2];
  const float* wq  = (const float*)d_in[3];
  const float* wk  = (const float*)d_in[4];
  const float* wv  = (const float*)d_in[5];
  const float* f1w = (const float*)d_in[6];
  const float* f1b = (const float*)d_in[7];
  const float* f2w = (const float*)d_in[8];
  const float* f2b = (const float*)d_in[9];
  float* out = (float*)d_out;

  // vt (40.96 MB) overlays embS+wt exactly: both dead after k_qkv.
  u16* vt      = (u16*)d_ws;                   // V^T [h*512+b][20][100], 20.48M u16
  u32* embS    = (u32*)d_ws;                   // 10M u32 = 40 MB (8 slice tables)
  u16* wt      = (u16*)d_ws + 20000000ull;
  u16* wtf     = (u16*)d_ws + 20480000ull;
  u16* click16 = wtf + 51200ull;               // also ctx16 ([bs][400])
  u16* c16     = click16 + 20480000ull;        // row-major QKV [51200][1200]
  float* alpha = (float*)(c16 + 61440000ull);  // [51200] f32

  k_slice<<<39064, 256, 0, stream>>>(emb, embS, alpha);
  k_trans_all<<<dim3(13, 13, 4), 256, 0, stream>>>(wq, wk, wv, f1w, wt, wtf);
  k_embed_s<<<20480, 256, 0, stream>>>(uc, embS, (u32*)click16);
  k_qkv_mfma<<<3000, 256, 0, stream>>>(click16, wt, c16);
  k_vt<<<2560, 256, 0, stream>>>((const u32*)c16, (u32*)vt);
  k_attn_mfma<<<BB * HH, 256, 0, stream>>>((const u32*)c16, vt, seq, click16);
  k_fc1_alpha<<<dim3(400, 2), 256, 0, stream>>>(click16, wtf, f1b, f2w, alpha);
  k_pool<<<BB, 256, 0, stream>>>(alpha, f2b, seq, click16, out);
}

// Round 12
// 548.590 us; speedup vs baseline: 1.0939x; 1.0939x over previous
//
#include <hip/hip_runtime.h>
#include <hip/hip_bf16.h>

using u16 = unsigned short;
using u32 = unsigned int;

#define BB 512
#define SS 100
#define LL 30
#define DD 400
#define MM 128
#define HH 20
#define DHH 20

typedef short v8s __attribute__((ext_vector_type(8)));   // 8 bf16 = 4 VGPR
typedef float v4f __attribute__((ext_vector_type(4)));   // MFMA 16x16 acc

__device__ __forceinline__ float lo2f(u32 u) { return __uint_as_float(u << 16); }
__device__ __forceinline__ float hi2f(u32 u) { return __uint_as_float(u & 0xffff0000u); }
__device__ __forceinline__ float bf2f(u16 h) { return __uint_as_float(((u32)h) << 16); }
__device__ __forceinline__ u16 f2bf(float f) {
  u32 u = __float_as_uint(f);
  u += 0x7fffu + ((u >> 16) & 1u);
  return (u16)(u >> 16);
}
__device__ __forceinline__ u32 packf2(float a, float b) {
  return (u32)f2bf(a) | (((u32)f2bf(b)) << 16);
}

// ---------------------------------------------------------------------------
// K0a: slice-reorganize the f32 emb table into 8 XCD-affine bf16 slice
// tables: embS[slice][row][25 u32] (5 MB per slice).  Also zeros alpha.
// ---------------------------------------------------------------------------
__global__ __launch_bounds__(256) void k_slice(const float* __restrict__ emb,
                                               u32* __restrict__ embS,
                                               float* __restrict__ alpha) {
  const int bid = blockIdx.x;                // 39064 blocks
  const int slice = bid & 7;
  const int inner = (bid >> 3) * 256 + threadIdx.x;   // 0..1249999 within slice
  if (bid < 200) alpha[bid * 256 + threadIdx.x] = 0.f;
  if (inner < 1250000) {
    const int c = inner % 25;
    const int row = inner / 25;
    const float2 v = *(const float2*)&emb[(size_t)row * DD + (slice * 25 + c) * 2];
    embS[(size_t)slice * 1250000u + inner] = packf2(v.x, v.y);
  }
}

// ---------------------------------------------------------------------------
// K0b: transpose-convert, all four weight matrices in one launch.
// ---------------------------------------------------------------------------
__global__ __launch_bounds__(256) void k_trans_all(const float* __restrict__ wq,
    const float* __restrict__ wk, const float* __restrict__ wv,
    const float* __restrict__ f1w, u16* __restrict__ wt, u16* __restrict__ wtf) {
  __shared__ float ts[32][33];
  const int z = blockIdx.z;
  const float* src = (z == 0) ? wq : (z == 1) ? wk : (z == 2) ? wv : f1w;
  u16* dst = (z < 3) ? (wt + (size_t)z * 160000) : wtf;
  const int N = (z < 3) ? 400 : 128;
  const int K = 400;
  const int t = threadIdx.x;
  const int n0 = blockIdx.x * 32, k0 = blockIdx.y * 32;
  const int c = t & 31, r8 = t >> 5;
#pragma unroll
  for (int i = 0; i < 4; ++i) {
    const int k = k0 + r8 + i * 8, n = n0 + c;
    ts[r8 + i * 8][c] = (k < K && n < N) ? src[(size_t)k * N + n] : 0.f;
  }
  __syncthreads();
#pragma unroll
  for (int i = 0; i < 4; ++i) {
    const int n = n0 + r8 + i * 8, k = k0 + c;
    if (n < N && k < K) dst[(size_t)n * K + k] = f2bf(ts[c][r8 + i * 8]);
  }
}

// ---------------------------------------------------------------------------
// K1: embedding gather + mean pool over XCD-affine slice tables.
// (round-6 form — accepted floor.)
// ---------------------------------------------------------------------------
__global__ __launch_bounds__(256) void k_embed_s(const int* __restrict__ uc,
                                                 const u32* __restrict__ embS,
                                                 u32* __restrict__ click) {
  __shared__ int sIdx[600];                  // 20 rows x 30 indices
  const int slice = blockIdx.x & 7;
  const int chunk = blockIdx.x >> 3;         // 0..2559
  const int bs0 = chunk * 20;
  const int t = threadIdx.x;
  for (int i = t; i < 600; i += 256) sIdx[i] = uc[(size_t)bs0 * LL + i];
  __syncthreads();
  if (t >= 250) return;
  const int g = t / 25, c = t % 25;
  const u32* base = embS + (size_t)slice * 50000u * 25u + c;
  float a0 = 0.f, a1 = 0.f, b0 = 0.f, b1 = 0.f;
  const int* i0 = &sIdx[g * 30];
  const int* i1 = &sIdx[(g + 10) * 30];
#pragma unroll 6
  for (int l = 0; l < LL; ++l) {
    const u32 v0 = base[(size_t)i0[l] * 25];
    const u32 v1 = base[(size_t)i1[l] * 25];
    a0 += lo2f(v0); a1 += hi2f(v0);
    b0 += lo2f(v1); b1 += hi2f(v1);
  }
  const float s = 1.0f / (float)LL;
  click[(size_t)(bs0 + g) * 200 + slice * 25 + c]      = packf2(a0 * s, a1 * s);
  click[(size_t)(bs0 + g + 10) * 200 + slice * 25 + c] = packf2(b0 * s, b1 * s);
}

// ---------------------------------------------------------------------------
// K2: QKV projection, bf16 MFMA.  1D grid 6000, BM=128.
//  - Counters proved (r11): conflicts=0 (swizzle), FETCH=40MB (XCD-affine),
//    barriers halved — time unmoved at Occupancy 21.7% (3 blocks/CU, 43KB).
//    => latency-bound on TLP.  BM 256->128: LDS 26KB -> 6 blocks/CU,
//    24 waves/CU, acc VGPR halved.  Everything else preserved.
//  - XCD-affine: xcd = bid%8 owns m-tiles [xcd*50, xcd*50+50) of 128 rows.
//  - BK=64 swizzled rows (128 B), XOR-16B-unit swizzle write+read.
// ROW-MAJOR output C[51200][1200].
// ---------------------------------------------------------------------------
__global__ __launch_bounds__(256) void k_qkv_mfma(const u16* __restrict__ A,
    const u16* __restrict__ Wt, u16* __restrict__ C) {
  __shared__ u16 As[128 * 64];   // row r at As[r*64], 16B-unit swizzled
  __shared__ u16 Bs[80 * 64];
  const int t = threadIdx.x;
  const int wave = t >> 6, lane = t & 63;
  const int q = lane >> 4, l16 = lane & 15;
  const int bid = blockIdx.x;                // 0..5999
  const int xcd = bid & 7, j = bid >> 3;     // j 0..749
  const int m_local = j / 15, mtn = j % 15;  // m_local 0..49
  const int m0 = (xcd * 50 + m_local) * 128;
  const int mat = mtn / 5, ntile = mtn % 5;
  const int nb = ntile * 80;
  const u16* Bt = Wt + (size_t)(mat * 400 + nb) * 400;
  const int mw = wave * 32;

  v4f acc[2][5];
#pragma unroll
  for (int i = 0; i < 2; ++i)
#pragma unroll
    for (int j2 = 0; j2 < 5; ++j2) acc[i][j2] = (v4f){0.f, 0.f, 0.f, 0.f};

  for (int kt = 0; kt < 7; ++kt) {
    const int k0 = kt * 64;
    // stage A: 128 rows x 8 units (1024 uint4)
#pragma unroll
    for (int i = 0; i < 4; ++i) {
      const int id = i * 256 + t;
      const int r = id >> 3, u = id & 7;     // u = 16B unit (8 u16)
      uint4 val = make_uint4(0u, 0u, 0u, 0u);
      if (k0 + u * 8 < 400) val = *(const uint4*)&A[(size_t)(m0 + r) * 400 + k0 + u * 8];
      *(uint4*)&As[r * 64 + ((u ^ (r & 7)) << 3)] = val;
    }
    // stage B: 80 rows x 8 units (640 uint4)
#pragma unroll
    for (int i = 0; i < 3; ++i) {
      const int id = i * 256 + t;
      if (id < 640) {
        const int n = id >> 3, u = id & 7;
        uint4 val = make_uint4(0u, 0u, 0u, 0u);
        if (k0 + u * 8 < 400) val = *(const uint4*)&Bt[(size_t)n * 400 + k0 + u * 8];
        *(uint4*)&Bs[n * 64 + ((u ^ (n & 7)) << 3)] = val;
      }
    }
    __syncthreads();
#pragma unroll
    for (int half = 0; half < 2; ++half) {
      const int qh = q + half * 4;           // unit 0-3 (k 0-31) or 4-7 (k 32-63)
      v8s a[2], b[5];
#pragma unroll
      for (int ms = 0; ms < 2; ++ms) {
        const int ra = mw + ms * 16 + l16;
        a[ms] = *(const v8s*)&As[ra * 64 + ((qh ^ (ra & 7)) << 3)];
      }
#pragma unroll
      for (int ns = 0; ns < 5; ++ns) {
        const int rb = ns * 16 + l16;
        b[ns] = *(const v8s*)&Bs[rb * 64 + ((qh ^ (rb & 7)) << 3)];
      }
#pragma unroll
      for (int ms = 0; ms < 2; ++ms)
#pragma unroll
        for (int ns = 0; ns < 5; ++ns)
          acc[ms][ns] = __builtin_amdgcn_mfma_f32_16x16x32_bf16(a[ms], b[ns], acc[ms][ns], 0, 0, 0);
    }
    __syncthreads();
  }
  // epilogue: row-major coalesced store.  D layout col = l16, row = q*4+reg
#pragma unroll
  for (int ms = 0; ms < 2; ++ms)
#pragma unroll
    for (int ns = 0; ns < 5; ++ns) {
      const v4f c = acc[ms][ns];
      const int gcol = mat * 400 + nb + ns * 16 + l16;
#pragma unroll
      for (int reg = 0; reg < 4; ++reg) {
        const int m = m0 + mw + ms * 16 + q * 4 + reg;
        C[(size_t)m * 1200 + gcol] = f2bf(c[reg]);
      }
    }
}

// ---------------------------------------------------------------------------
// K2b: V transpose from row-major C.  Chunk c = h*512+b; input rows
// C[b*100+s][800+h*20 .. +20), output [20][100] contiguous at c*2000 u16.
// LDS tile padded [100][22] (gcd(11,32)=1) -> conflict-free.
// ---------------------------------------------------------------------------
__global__ __launch_bounds__(256) void k_vt(const u32* __restrict__ c32,
                                            u32* __restrict__ vout) {
  __shared__ u16 Vs[4][100][22];
  const int wave = threadIdx.x >> 6, lane = threadIdx.x & 63;
  const int c = blockIdx.x * 4 + wave;       // h*512+b
  const int h = c >> 9, b = c & 511;
  const u32* in = c32 + (size_t)b * 60000 + 400 + h * 10;
  u32* out = vout + (size_t)c * 1000;
  for (int i = lane; i < 1000; i += 64) {
    const int s = i / 10, dp = i % 10;
    *(u32*)&Vs[wave][s][dp * 2] = in[s * 600 + dp];
  }
  __syncthreads();
  for (int o = lane; o < 1000; o += 64) {
    const int d = o / 50, sc = o % 50;
    out[o] = (u32)Vs[wave][2 * sc][d] | (((u32)Vs[wave][2 * sc + 1][d]) << 16);
  }
}

// ---------------------------------------------------------------------------
// K3: MFMA attention, swapped-QK / register-softmax form.
// Q/K read from row-major C (cols h*20.. / 400+h*20..); V^T from k_vt.
// One block per (b,h), 4 waves, LDS = K only (8.96 KB), single barrier.
// ---------------------------------------------------------------------------
__global__ __launch_bounds__(256) void k_attn_mfma(const u32* __restrict__ c32,
    const u16* __restrict__ vtg, const int* __restrict__ seq,
    u16* __restrict__ ctxg) {
  __shared__ u32 Ks[2240];                 // [112 rows][20 u32] zero-padded K
  const int b = blockIdx.x / HH, h = blockIdx.x % HH;
  const int t = threadIdx.x;
  const int wave = t >> 6, lane = t & 63;
  const int quad = lane >> 4, l16 = lane & 15;
  const int len = seq[b];
  const u32* qp = c32 + (size_t)b * 60000 + h * 10;        // Q cols
  const u32* kp = qp + 200;                                // K cols (+400 u16)
  const u32* vb = (const u32*)(vtg + (size_t)(h * 512 + b) * 2000);

  // V^T B-fragments direct from global, hoisted across both mt iterations.
  uint2 vfr[2][7];
#pragma unroll
  for (int dt = 0; dt < 2; ++dt) {
    const int d = dt * 16 + l16;
#pragma unroll
    for (int nt = 0; nt < 7; ++nt)
      vfr[dt][nt] = *(const uint2*)(vb + d * 50 + nt * 8 + quad * 2);
  }
  // stage K into LDS, zero-padded
  for (int id = t; id < 2240; id += 256) {
    const int r = id / 20, c = id % 20;
    Ks[id] = (r < 100 && c < 10) ? kp[(size_t)r * 600 + c] : 0u;
  }
  __syncthreads();

  const float sc = 0.2236067977499790f;  // 1/sqrt(20)
  u16* cb = ctxg + (size_t)b * SS * DD + h * DHH;
  for (int mi = 0; mi < 2; ++mi) {
    const int mt = wave + mi * 4;
    if (mt >= 7) break;
    // Q fragment (B-slot): row mt*16+l16 (clamped; rows>=100 discarded),
    // k = quad*8..+8 (k>=20 garbage annihilated by K's zero pad).
    const int qrow = mt * 16 + l16;
    const int qr = (qrow < 100) ? qrow : 0;
    union { uint2 u[2]; v8s v; } qf;
    qf.u[0] = *(const uint2*)(qp + (size_t)qr * 600 + quad * 4);
    qf.u[1] = *(const uint2*)(qp + (size_t)qr * 600 + quad * 4 + 2);
    // swapped QK^T: acc[nt][reg] = S[q = mt*16+l16][k = nt*16+quad*4+reg]
    v4f acc[7];
#pragma unroll
    for (int nt = 0; nt < 7; ++nt) {
      const v8s kf = *(const v8s*)&Ks[(nt * 16 + l16) * 20 + quad * 4];
      acc[nt] = __builtin_amdgcn_mfma_f32_16x16x32_bf16(kf, qf.v, (v4f){0.f,0.f,0.f,0.f}, 0, 0, 0);
    }
    // in-register row softmax (row spread across the 4 quads only)
    float mx = -3.0e38f;
#pragma unroll
    for (int nt = 0; nt < 7; ++nt)
#pragma unroll
      for (int reg = 0; reg < 4; ++reg) {
        const int k = nt * 16 + quad * 4 + reg;
        const float v = acc[nt][reg] * sc + ((k < len) ? 1.0f : -1e9f);
        acc[nt][reg] = v;
        mx = fmaxf(mx, v);
      }
    mx = fmaxf(mx, __shfl_xor(mx, 16));
    mx = fmaxf(mx, __shfl_xor(mx, 32));
    float sum = 0.f;
#pragma unroll
    for (int nt = 0; nt < 7; ++nt)
#pragma unroll
      for (int reg = 0; reg < 4; ++reg) {
        const float e = __expf(acc[nt][reg] - mx);
        acc[nt][reg] = e;
        sum += e;
      }
    sum += __shfl_xor(sum, 16);
    sum += __shfl_xor(sum, 32);
    const float inv = 1.0f / sum;
    // PV: P already in A-fragment layout (k = quad*4+j); zero-extended
    // 16x16x32 MFMAs (operands in slots quad*8+{0..3}, zeros above).
    v4f o0 = (v4f){0.f, 0.f, 0.f, 0.f}, o1 = o0;
#pragma unroll
    for (int nt = 0; nt < 7; ++nt) {
      union { u32 u[4]; v8s v; } pa, vb0, vb1;
      pa.u[0] = packf2(acc[nt][0] * inv, acc[nt][1] * inv);
      pa.u[1] = packf2(acc[nt][2] * inv, acc[nt][3] * inv);
      pa.u[2] = 0u; pa.u[3] = 0u;
      vb0.u[0] = vfr[0][nt].x; vb0.u[1] = vfr[0][nt].y; vb0.u[2] = 0u; vb0.u[3] = 0u;
      vb1.u[0] = vfr[1][nt].x; vb1.u[1] = vfr[1][nt].y; vb1.u[2] = 0u; vb1.u[3] = 0u;
      o0 = __builtin_amdgcn_mfma_f32_16x16x32_bf16(pa.v, vb0.v, o0, 0, 0, 0);
      o1 = __builtin_amdgcn_mfma_f32_16x16x32_bf16(pa.v, vb1.v, o1, 0, 0, 0);
    }
#pragma unroll
    for (int reg = 0; reg < 4; ++reg) {
      const int q2 = mt * 16 + quad * 4 + reg;
      if (q2 < 100) {
        cb[(size_t)q2 * DD + l16] = f2bf(o0[reg]);
        if (l16 < 4) cb[(size_t)q2 * DD + 16 + l16] = f2bf(o1[reg]);
      }
    }
  }
}

// ---------------------------------------------------------------------------
// K4: alpha = tanh(ctx @ fc1_w + f1b) · f2w, fused.
// ---------------------------------------------------------------------------
__global__ __launch_bounds__(256) void k_fc1_alpha(const u16* __restrict__ A,
    const u16* __restrict__ Bt, const float* __restrict__ f1b,
    const float* __restrict__ f2w, float* __restrict__ alpha) {
  __shared__ u16 As[128][40];
  __shared__ u16 Bs[64][40];
  const int t = threadIdx.x;
  const int wave = t >> 6, lane = t & 63;
  const int quad = lane >> 4, l16 = lane & 15;
  const int m0 = blockIdx.x * 128;
  const int nb = blockIdx.y * 64;
  const int mw = wave * 32;
  v4f acc[2][4];
#pragma unroll
  for (int i = 0; i < 2; ++i)
#pragma unroll
    for (int j = 0; j < 4; ++j) acc[i][j] = (v4f){0.f, 0.f, 0.f, 0.f};

  for (int kt = 0; kt < 13; ++kt) {
    const int k0 = kt * 32;
#pragma unroll
    for (int i = 0; i < 2; ++i) {
      const int id = i * 256 + t;
      const int r = id >> 2, ko = (id & 3) * 8;
      uint4 val = make_uint4(0u, 0u, 0u, 0u);
      if (k0 + ko < 400) val = *(const uint4*)&A[(size_t)(m0 + r) * 400 + k0 + ko];
      *(uint4*)&As[r][ko] = val;
    }
    {
      const int r = t >> 2, ko = (t & 3) * 8;
      uint4 val = make_uint4(0u, 0u, 0u, 0u);
      if (k0 + ko < 400) val = *(const uint4*)&Bt[(size_t)(nb + r) * 400 + k0 + ko];
      *(uint4*)&Bs[r][ko] = val;
    }
    __syncthreads();
    v8s a[2], b[4];
#pragma unroll
    for (int ms = 0; ms < 2; ++ms) a[ms] = *(const v8s*)&As[mw + ms * 16 + l16][quad * 8];
#pragma unroll
    for (int ns = 0; ns < 4; ++ns) b[ns] = *(const v8s*)&Bs[ns * 16 + l16][quad * 8];
#pragma unroll
    for (int ms = 0; ms < 2; ++ms)
#pragma unroll
      for (int ns = 0; ns < 4; ++ns)
        acc[ms][ns] = __builtin_amdgcn_mfma_f32_16x16x32_bf16(a[ms], b[ns], acc[ms][ns], 0, 0, 0);
    __syncthreads();
  }
  float fwv[4], fbv[4];
#pragma unroll
  for (int ns = 0; ns < 4; ++ns) {
    fwv[ns] = f2w[nb + ns * 16 + l16];
    fbv[ns] = f1b[nb + ns * 16 + l16];
  }
#pragma unroll
  for (int ms = 0; ms < 2; ++ms)
#pragma unroll
    for (int reg = 0; reg < 4; ++reg) {
      float p = 0.f;
#pragma unroll
      for (int ns = 0; ns < 4; ++ns)
        p += tanhf(acc[ms][ns][reg] + fbv[ns]) * fwv[ns];
#pragma unroll
      for (int o = 1; o < 16; o <<= 1) p += __shfl_xor(p, o);
      if (l16 == 0)
        atomicAdd(&alpha[m0 + mw + ms * 16 + quad * 4 + reg], p);
    }
}

// ---------------------------------------------------------------------------
// K5: additive attention pooling from alpha.  One block per batch row.
// ---------------------------------------------------------------------------
__global__ __launch_bounds__(256) void k_pool(const float* __restrict__ alpha,
    const float* __restrict__ f2b, const int* __restrict__ seq,
    const u16* __restrict__ ctxg, float* __restrict__ out) {
  const int b = blockIdx.x;
  const int t = threadIdx.x, w = t >> 6, lane = t & 63;
  __shared__ float wts[SS];
  const int len = seq[b];
  const float bias = f2b[0];
  if (t < SS) wts[t] = alpha[b * SS + t] + bias + ((t < len) ? 1.0f : -1e9f);
  __syncthreads();
  if (w == 0) {
    const float v0 = wts[lane];
    const float v1 = (lane + 64 < SS) ? wts[lane + 64] : -3.0e38f;
    float mx = fmaxf(v0, v1);
#pragma unroll
    for (int o = 32; o > 0; o >>= 1) mx = fmaxf(mx, __shfl_xor(mx, o));
    const float e0 = __expf(v0 - mx);
    const float e1 = (lane + 64 < SS) ? __expf(v1 - mx) : 0.f;
    float sm = e0 + e1;
#pragma unroll
    for (int o = 32; o > 0; o >>= 1) sm += __shfl_xor(sm, o);
    const float inv = 1.0f / sm;
    wts[lane] = e0 * inv;
    if (lane + 64 < SS) wts[lane + 64] = e1 * inv;
  }
  __syncthreads();
  for (int d = t; d < DD; d += 256) {
    float acc = 0.f;
    const u16* cb = ctxg + (size_t)b * SS * DD + d;
    for (int s = 0; s < SS; ++s) acc += wts[s] * bf2f(cb[(size_t)s * DD]);
    out[(size_t)b * DD + d] = acc;
  }
}

// ---------------------------------------------------------------------------
extern "C" void kernel_launch(void* const* d_in, const int* in_sizes, int n_in,
                              void* d_out, int out_size, void* d_ws, size_t ws_size,
                              hipStream_t stream) {
  const int*   uc  = (const int*)d_in[0];
  const int*   seq = (const int*)d_in[1];
  const float* emb = (const float*)d_in[2];
  const float* wq  = (const float*)d_in[3];
  const float* wk  = (const float*)d_in[4];
  const float* wv  = (const float*)d_in[5];
  const float* f1w = (const float*)d_in[6];
  const float* f1b = (const float*)d_in[7];
  const float* f2w = (const float*)d_in[8];
  const float* f2b = (const float*)d_in[9];
  float* out = (float*)d_out;

  // vt (40.96 MB) overlays embS+wt exactly: both dead after k_qkv.
  u16* vt      = (u16*)d_ws;                   // V^T [h*512+b][20][100], 20.48M u16
  u32* embS    = (u32*)d_ws;                   // 10M u32 = 40 MB (8 slice tables)
  u16* wt      = (u16*)d_ws + 20000000ull;
  u16* wtf     = (u16*)d_ws + 20480000ull;
  u16* click16 = wtf + 51200ull;               // also ctx16 ([bs][400])
  u16* c16     = click16 + 20480000ull;        // row-major QKV [51200][1200]
  float* alpha = (float*)(c16 + 61440000ull);  // [51200] f32

  k_slice<<<39064, 256, 0, stream>>>(emb, embS, alpha);
  k_trans_all<<<dim3(13, 13, 4), 256, 0, stream>>>(wq, wk, wv, f1w, wt, wtf);
  k_embed_s<<<20480, 256, 0, stream>>>(uc, embS, (u32*)click16);
  k_qkv_mfma<<<6000, 256, 0, stream>>>(click16, wt, c16);
  k_vt<<<2560, 256, 0, stream>>>((const u32*)c16, (u32*)vt);
  k_attn_mfma<<<BB * HH, 256, 0, stream>>>((const u32*)c16, vt, seq, click16);
  k_fc1_alpha<<<dim3(400, 2), 256, 0, stream>>>(click16, wtf, f1b, f2w, alpha);
  k_pool<<<BB, 256, 0, stream>>>(alpha, f2b, seq, click16, out);
}